// Round 11
// baseline (1283.781 us; speedup 1.0000x reference)
//
#include <hip/hip_runtime.h>
#include <hip/hip_bf16.h>

#define BATCH 131072
#define H 256
#define NBLK 8
#define NMID 3
#define MS 16            // samples per instance; WG = 2 instances (S0,S1)
#define RT_N 3           // 3 streams * 16 rows / 16 = 3 row-tiles
#define NT 256           // 4 waves; each wave owns one 64-col group (cg)

typedef __attribute__((ext_vector_type(8))) short short8;   // 8 bf16 = 4 VGPRs (MFMA A/B frag)
typedef __attribute__((ext_vector_type(4))) float f32x4;    // MFMA C/D frag

// pack two f32 -> two bf16 (round-half-up): 2 adds + v_perm. Cold paths.
__device__ __forceinline__ unsigned pk2(float a, float b) {
    unsigned ua = __float_as_uint(a) + 0x8000u;
    unsigned ub = __float_as_uint(b) + 0x8000u;
    return __builtin_amdgcn_perm(ub, ua, 0x07060302u);
}
// hot-path pack: single-instruction RNE pack (low16 = bf(a), high16 = bf(b))
__device__ __forceinline__ unsigned cpk(float a, float b) {
    unsigned r;
    asm("v_cvt_pk_bf16_f32 %0, %1, %2" : "=v"(r) : "v"(a), "v"(b));
    return r;
}

// Pack Wm into MFMA B-frag order bf16 with COLUMN-PERMUTED tiles:
// tile T covers physical cols n = (T>>2)*64 + m*4 + (T&3), m = lane&15.
__global__ void pack_w_kernel(const float* __restrict__ Wm, unsigned short* __restrict__ Wp) {
    int o = blockIdx.x * blockDim.x + threadIdx.x;   // 24 * 8192 chunks
    if (o >= NBLK * NMID * 8192) return;
    int lane  = o & 63;
    int T     = (o >> 6) & 15;
    int kk    = (o >> 10) & 7;
    int layer = o >> 13;
    int n  = (T >> 2) * 64 + (lane & 15) * 4 + (T & 3);
    int k0 = kk * 32 + (lane >> 4) * 8;
    const float* src = Wm + (size_t)layer * H * H;
    unsigned int w[4];
    #pragma unroll
    for (int jj = 0; jj < 4; ++jj)
        w[jj] = pk2(src[(size_t)(k0 + 2*jj) * H + n], src[(size_t)(k0 + 2*jj + 1) * H + n]);
    uint4 val; val.x = w[0]; val.y = w[1]; val.z = w[2]; val.w = w[3];
    ((uint4*)Wp)[o] = val;
}

// ReLU on primal (bias in acc[0] via C-init), mask tangents, write next X.
// kk-parity slot swizzle: conflict-free b64 stores; readers xor kk&1.
__device__ __forceinline__ void epilogue_write(const f32x4 (&acc)[RT_N][4],
                                               unsigned short* __restrict__ Xs,
                                               int cg, int lane) {
    const int mcol = lane & 15, quad = lane >> 4;
    const int nb  = cg * 64 + mcol * 4;
    const int kkx = nb >> 5;
    const int qx  = (nb >> 3) & 3;
    const int jb  = nb & 7;
    const int kx1 = kkx & 1;
    #pragma unroll
    for (int r = 0; r < 4; ++r) {
        float hv[4], ta[4], tb[4];
        #pragma unroll
        for (int c = 0; c < 4; ++c) {
            float pre = acc[0][c][r];
            bool mk = pre > 0.0f;
            hv[c] = fmaxf(pre, 0.0f);
            ta[c] = mk ? acc[1][c][r] : 0.0f;
            tb[c] = mk ? acc[2][c][r] : 0.0f;
        }
        int le  = qx * 16 + quad * 4 + r;
        int scl = (le ^ ((le >> 3) & 7)) ^ kx1;
        int e0  = ((kkx * 64 + scl) * 8) + jb;
        uint2 ph; ph.x = cpk(hv[0], hv[1]); ph.y = cpk(hv[2], hv[3]);
        uint2 pa; pa.x = cpk(ta[0], ta[1]); pa.y = cpk(ta[2], ta[3]);
        uint2 pb; pb.x = cpk(tb[0], tb[1]); pb.y = cpk(tb[2], tb[3]);
        *(uint2*)(Xs + e0)         = ph;
        *(uint2*)(Xs + e0 + 4096)  = pa;
        *(uint2*)(Xs + e0 + 8192)  = pb;
    }
}

__device__ __forceinline__ void fill_x(uint4* __restrict__ Xl4,
                                       const float* __restrict__ zb, int tid) {
    if (tid < 192) {
        int st = tid >> 6, cl = tid & 63;
        int l = cl ^ ((cl >> 3) & 7);
        int m = l & 15, q = l >> 4;
        uint4 pk = {0u, 0u, 0u, 0u};
        if (q == 0) {
            if (st == 0)      pk.x = pk2(zb[m*2+0], zb[m*2+1]);
            else if (st == 1) pk.x = 0x00003F80u;   // (1,0)
            else              pk.x = 0x3F800000u;   // (0,1)
        }
        Xl4[st * 512 + cl] = pk;
    }
}

__device__ __forceinline__ void acc_init(f32x4 (&acc)[RT_N][4], float4 bv) {
    #pragma unroll
    for (int ct = 0; ct < 4; ++ct) {
        float bb = (ct == 0) ? bv.x : (ct == 1) ? bv.y : (ct == 2) ? bv.z : bv.w;
        acc[0][ct] = (f32x4){bb, bb, bb, bb};   // bias via C-operand
        acc[1][ct] = (f32x4){0.f, 0.f, 0.f, 0.f};
        acc[2][ct] = (f32x4){0.f, 0.f, 0.f, 0.f};
    }
}

__device__ __forceinline__ void l0_mfma(f32x4 (&acc)[RT_N][4], const uint4* __restrict__ Xl4,
                                        const short8 (&b0f)[4], float4 bv, int rl) {
    acc_init(acc, bv);
    #pragma unroll
    for (int st = 0; st < RT_N; ++st) {
        short8 af = ((const short8*)Xl4)[(st * 8) * 64 + rl];
        #pragma unroll
        for (int ct = 0; ct < 4; ++ct)
            acc[st][ct] = __builtin_amdgcn_mfma_f32_16x16x32_bf16(af, b0f[ct], acc[st][ct], 0, 0, 0);
    }
}

__device__ __forceinline__ void mid_mfma(f32x4 (&acc)[RT_N][4], const uint4* __restrict__ Xl4,
                                         const short8* __restrict__ Bp, float4 bv,
                                         int cg, int lane, int rl) {
    acc_init(acc, bv);
    #pragma unroll 2
    for (int kk = 0; kk < 8; ++kk) {
        short8 bf[4];
        #pragma unroll
        for (int ct = 0; ct < 4; ++ct)
            bf[ct] = Bp[(kk*16 + cg*4 + ct)*64 + lane];          // coalesced b128 (L2-hot)
        const int rls = rl ^ (kk & 1);
        #pragma unroll
        for (int st = 0; st < RT_N; ++st) {
            short8 af = ((const short8*)Xl4)[(st*8 + kk)*64 + rls]; // ds_read_b128
            #pragma unroll
            for (int ct = 0; ct < 4; ++ct)
                acc[st][ct] = __builtin_amdgcn_mfma_f32_16x16x32_bf16(af, bf[ct], acc[st][ct], 0, 0, 0);
        }
    }
}

__device__ __forceinline__ void l4_mfma(f32x4 (&accL)[RT_N], const uint4* __restrict__ Xl4,
                                        const short8 (&b4)[2], int cg, int rl) {
    #pragma unroll
    for (int st = 0; st < RT_N; ++st) accL[st] = (f32x4){0.f, 0.f, 0.f, 0.f};
    #pragma unroll
    for (int kki = 0; kki < 2; ++kki) {
        const int rls = rl ^ (kki & 1);      // chunk kk=cg*2+kki: parity = kki&1
        #pragma unroll
        for (int st = 0; st < RT_N; ++st) {
            short8 a0 = ((const short8*)Xl4)[(st*8 + cg*2 + kki)*64 + rls];
            accL[st] = __builtin_amdgcn_mfma_f32_16x16x32_bf16(a0, b4[kki], accL[st], 0, 0, 0);
        }
    }
}

__device__ __forceinline__ void l4_part(const f32x4 (&accL)[RT_N], float* __restrict__ part,
                                        int cg, int mcol, int quad) {
    if (mcol < 2) {
        #pragma unroll
        for (int st = 0; st < RT_N; ++st)
            #pragma unroll
            for (int r = 0; r < 4; ++r)
                part[((st*16 + quad*4 + r)*2 + mcol)*4 + cg] = accL[st][r];
    }
}

__device__ __forceinline__ void l4_tail(const float* __restrict__ part,
                                        float* __restrict__ zb, const float* __restrict__ vb,
                                        float& dlp, const float* __restrict__ bob, int tid) {
    if (tid < MS) {
        const float4* p4 = (const float4*)part;
        const int r0 = tid * 2;
        float4 h0 = p4[r0],      h1 = p4[r0 + 1];
        float4 a0 = p4[r0 + 32], a1 = p4[r0 + 33];
        float4 t0 = p4[r0 + 64], t1 = p4[r0 + 65];
        float SH0 = (h0.x + h0.y) + (h0.z + h0.w);
        float SH1 = (h1.x + h1.y) + (h1.z + h1.w);
        float SA0 = (a0.x + a0.y) + (a0.z + a0.w);
        float SA1 = (a1.x + a1.y) + (a1.z + a1.w);
        float SB0 = (t0.x + t0.y) + (t0.z + t0.w);
        float SB1 = (t1.x + t1.y) + (t1.z + t1.w);
        float pre0 = SH0 + bob[0], pre1 = SH1 + bob[1];
        bool  m0 = pre0 > 0.f,     m1 = pre1 > 0.f;
        float gx0 = m0 ? pre0 : 0.f, gx1 = m1 ? pre1 : 0.f;
        float J00 = m0 ? SA0 : 0.f;
        float J01 = m0 ? SB0 : 0.f;
        float J10 = m1 ? SA1 : 0.f;
        float J11 = m1 ? SB1 : 0.f;
        float v0 = vb[tid*2+0], v1 = vb[tid*2+1];
        float w0 = v0, w1 = v1, ld = 0.f;
        const float coef[5] = {1.f, -0.5f, 1.f/3.f, -0.25f, 0.2f};
        #pragma unroll
        for (int k = 0; k < 5; ++k) {
            float nw0 = fmaf(J00, w0, J01 * w1);
            float nw1 = fmaf(J10, w0, J11 * w1);
            w0 = nw0; w1 = nw1;
            ld = fmaf(coef[k], fmaf(w0, v0, w1 * v1), ld);
        }
        zb[tid*2+0] += gx0;
        zb[tid*2+1] += gx1;
        dlp -= ld;
    }
}

// Two-instance software pipeline: every barrier-to-barrier segment pairs
// mfma(one instance) with epilogue(other instance) — independent streams,
// so the wave's in-order issue can fill MFMA pipe-stall slots with VALU.
__global__ __launch_bounds__(NT, 3)   // 3 waves/SIMD (VGPR cap 170), 3 WGs/CU by LDS
void flow_kernel(const float* __restrict__ x, const float* __restrict__ v,
                 const float* __restrict__ Wi, const float* __restrict__ bi,
                 const float* __restrict__ bm, const float* __restrict__ Wo,
                 const float* __restrict__ bo,
                 const unsigned short* __restrict__ Wp,
                 float* __restrict__ out)
{
    __shared__ uint4 X0[RT_N * 8 * 64];      // 24 KiB — instance S0
    __shared__ uint4 X1[RT_N * 8 * 64];      // 24 KiB — instance S1
    __shared__ float zbuf0[MS * 2], vbuf0[MS * 2];
    __shared__ float zbuf1[MS * 2], vbuf1[MS * 2];

    const int tid  = threadIdx.x;
    const int cg   = tid >> 6;
    const int lane = tid & 63;
    const int mcol = lane & 15;
    const int quad = lane >> 4;
    const int s0   = blockIdx.x * (2 * MS);
    const int rl   = lane ^ ((lane >> 3) & 7);

    float dlp0 = 0.0f, dlp1 = 0.0f;
    if (tid < 2 * MS) {
        int t = tid & 15;
        int s = s0 + tid;                    // S0: s0..+15, S1: s0+16..+31
        float* zb = (tid < MS) ? zbuf0 : zbuf1;
        float* vb = (tid < MS) ? vbuf0 : vbuf1;
        zb[t*2+0] = x[(size_t)s*2+0];
        zb[t*2+1] = x[(size_t)s*2+1];
        vb[t*2+0] = v[(size_t)s*2+0];
        vb[t*2+1] = v[(size_t)s*2+1];
    }

    {   // modest stagger across the 3 co-resident WGs
        const int slot = (blockIdx.x >> 8) % 3;
        for (int i = 0; i < slot; ++i) __builtin_amdgcn_s_sleep(10);
    }
    __syncthreads();

    for (int b = 0; b < NBLK; ++b) {
        // ---- seg0: F(S0)[b]  ∥  L4.tail(S1)[b-1] ----
        fill_x(X0, zbuf0, tid);
        if (b > 0) l4_tail((const float*)X1, zbuf1, vbuf1, dlp1, bo + (size_t)(b-1)*2, tid);
        __syncthreads();

        // per-b L0 weights (shared by both instances)
        const float* Wi0 = Wi + (size_t)b * 2 * H;
        const float* Wi1 = Wi0 + H;
        short8 b0f[4];
        #pragma unroll
        for (int ct = 0; ct < 4; ++ct) {
            short8 z = {0,0,0,0,0,0,0,0};
            if (lane < 16) {
                int n = cg * 64 + lane * 4 + ct;
                unsigned p = pk2(Wi0[n], Wi1[n]);
                z[0] = (short)(p & 0xFFFFu);
                z[1] = (short)(p >> 16);
            }
            b0f[ct] = z;
        }
        const float4 bv0 = *(const float4*)(bi + (size_t)b * H + cg * 64 + mcol * 4);

        f32x4 acc0[RT_N][4], acc1[RT_N][4];

        // ---- seg1: L0.mfma(S0) ∥ F(S1) ----
        fill_x(X1, zbuf1, tid);
        l0_mfma(acc0, X0, b0f, bv0, rl);
        __syncthreads();

        // ---- seg2: L0.epi(S0) ∥ L0.mfma(S1) ----
        l0_mfma(acc1, X1, b0f, bv0, rl);
        epilogue_write(acc0, (unsigned short*)X0, cg, lane);
        __syncthreads();

        // ---- mids: segA/segB per li ----
        for (int li = 0; li < NMID; ++li) {
            const int layer = b * NMID + li;
            const short8* Bp = ((const short8*)Wp) + (size_t)layer * 8192;
            const float4 bv  = *(const float4*)(bm + (size_t)layer * H + cg * 64 + mcol * 4);
            // segA: M(li).mfma(S0) ∥ M(li-1)/L0.epi(S1)
            mid_mfma(acc0, X0, Bp, bv, cg, lane, rl);
            epilogue_write(acc1, (unsigned short*)X1, cg, lane);
            __syncthreads();
            // segB: M(li).epi(S0) ∥ M(li).mfma(S1)
            mid_mfma(acc1, X1, Bp, bv, cg, lane, rl);
            epilogue_write(acc0, (unsigned short*)X0, cg, lane);
            __syncthreads();
        }

        // per-b L4 weights (shared by both instances)
        const float* Wob = Wo + (size_t)b * H * 2;
        short8 b4[2];
        #pragma unroll
        for (int kki = 0; kki < 2; ++kki) {
            short8 z = {0,0,0,0,0,0,0,0};
            if (mcol < 2) {
                int kb = (cg * 2 + kki) * 32 + quad * 8;
                #pragma unroll
                for (int jj = 0; jj < 4; ++jj) {
                    unsigned p = pk2(Wob[(kb + 2*jj) * 2 + mcol], Wob[(kb + 2*jj + 1) * 2 + mcol]);
                    z[2*jj]   = (short)(p & 0xFFFFu);
                    z[2*jj+1] = (short)(p >> 16);
                }
            }
            b4[kki] = z;
        }

        f32x4 accL0[RT_N], accL1[RT_N];

        // ---- seg9: L4.mfma(S0) ∥ M2.epi(S1) ----
        l4_mfma(accL0, X0, b4, cg, rl);
        epilogue_write(acc1, (unsigned short*)X1, cg, lane);
        __syncthreads();

        // ---- seg10: L4.part(S0) ∥ L4.mfma(S1) ----
        l4_mfma(accL1, X1, b4, cg, rl);
        l4_part(accL0, (float*)X0, cg, mcol, quad);
        __syncthreads();

        // ---- seg11: L4.tail(S0) ∥ L4.part(S1) ----
        l4_part(accL1, (float*)X1, cg, mcol, quad);
        l4_tail((const float*)X0, zbuf0, vbuf0, dlp0, bo + (size_t)b * 2, tid);
        __syncthreads();
    }

    // drain: L4.tail(S1)[NBLK-1]
    l4_tail((const float*)X1, zbuf1, vbuf1, dlp1, bo + (size_t)(NBLK-1)*2, tid);
    __syncthreads();

    if (tid < MS) {
        out[(size_t)(s0+tid)*2+0]      = zbuf0[tid*2+0];
        out[(size_t)(s0+tid)*2+1]      = zbuf0[tid*2+1];
        out[(size_t)(s0+MS+tid)*2+0]   = zbuf1[tid*2+0];
        out[(size_t)(s0+MS+tid)*2+1]   = zbuf1[tid*2+1];
        out[(size_t)2*BATCH + s0 + tid]      = dlp0;
        out[(size_t)2*BATCH + s0 + MS + tid] = dlp1;
    }
}

extern "C" void kernel_launch(void* const* d_in, const int* in_sizes, int n_in,
                              void* d_out, int out_size, void* d_ws, size_t ws_size,
                              hipStream_t stream) {
    const float* x  = (const float*)d_in[0];
    const float* v  = (const float*)d_in[1];
    const float* Wi = (const float*)d_in[2];
    const float* bi = (const float*)d_in[3];
    const float* Wm = (const float*)d_in[4];
    const float* bm = (const float*)d_in[5];
    const float* Wo = (const float*)d_in[6];
    const float* bo = (const float*)d_in[7];
    unsigned short* Wp = (unsigned short*)d_ws;   // 24*65536*2 = 3 MiB

    int nchunks = NBLK * NMID * 8192;
    pack_w_kernel<<<(nchunks + 255) / 256, 256, 0, stream>>>(Wm, Wp);
    flow_kernel<<<BATCH / (2 * MS), NT, 0, stream>>>(x, v, Wi, bi, bm, Wo, bo, Wp, (float*)d_out);
}